// Round 3
// baseline (476.880 us; speedup 1.0000x reference)
//
#include <hip/hip_runtime.h>

#define BL 16384   // B*L
#define LQ 4096    // L
#define VPS 136    // vpL row stride in halves (16B-aligned rows, breaks pow2 banks)

typedef unsigned int uint;
typedef unsigned short ushort;
typedef __attribute__((ext_vector_type(8))) short short8;
typedef __attribute__((ext_vector_type(4))) float floatx4;

union F8 { uint u[4]; uint4 u4; short8 s; };

static __device__ __forceinline__ uint f2bf(float f) {
    uint x = __float_as_uint(f);
    x += 0x7fffu + ((x >> 16) & 1u);   // RTNE
    return x >> 16;
}
static __device__ __forceinline__ float bf2f(uint h) { return __uint_as_float(h << 16); }
static __device__ __forceinline__ uint pk(float lo, float hi) {
    return f2bf(lo) | (f2bf(hi) << 16);
}

// ============ Kernel 1: QKV projection, split-bf16 MFMA (unchanged from R2) ============
__global__ __launch_bounds__(256, 4) void qkv_mfma(
    const float* __restrict__ x, const float* __restrict__ Wq,
    const float* __restrict__ Wk, const float* __restrict__ Wv,
    float* __restrict__ qkvb)
{
    __shared__ uint4 wfh[4][8][64];
    __shared__ uint4 wfl[4][8][64];
    const int tid  = threadIdx.x;
    const int lane = tid & 63;
    const int w    = tid >> 6;
    const int q    = lane >> 4;
    const int c    = lane & 15;
    const int proj = blockIdx.y;
    const float* W = (proj == 0) ? Wq : (proj == 1) ? Wk : Wv;
    float* outb = qkvb + (size_t)proj * BL * 128;

    for (int e = tid; e < 32 * 64; e += 256) {
        const int f = e >> 6, ln = e & 63;
        const int ks = f >> 3, Nt = f & 7;
        const int lq = ln >> 4, lc = ln & 15;
        const float* wp = W + (ks * 32 + lq * 8) * 128 + Nt * 16 + lc;
        F8 hi, lo;
        #pragma unroll
        for (int j = 0; j < 4; ++j) {
            const float a = wp[(2 * j) * 128], b = wp[(2 * j + 1) * 128];
            const uint ha = f2bf(a), hb = f2bf(b);
            hi.u[j] = ha | (hb << 16);
            lo.u[j] = pk(a - bf2f(ha), b - bf2f(hb));
        }
        wfh[ks][Nt][ln] = hi.u4;
        wfl[ks][Nt][ln] = lo.u4;
    }
    __syncthreads();

    floatx4 acc[8];
    #pragma unroll
    for (int i = 0; i < 8; ++i) acc[i] = {0.f, 0.f, 0.f, 0.f};

    const int arow = blockIdx.x * 64 + w * 16 + c;
    #pragma unroll
    for (int ks = 0; ks < 4; ++ks) {
        const float* xp = x + arow * 128 + ks * 32 + q * 8;
        const float4 xa = ((const float4*)xp)[0];
        const float4 xb = ((const float4*)xp)[1];
        const float xv[8] = {xa.x, xa.y, xa.z, xa.w, xb.x, xb.y, xb.z, xb.w};
        F8 xh, xl;
        #pragma unroll
        for (int j = 0; j < 4; ++j) {
            const uint ha = f2bf(xv[2 * j]), hb = f2bf(xv[2 * j + 1]);
            xh.u[j] = ha | (hb << 16);
            xl.u[j] = pk(xv[2 * j] - bf2f(ha), xv[2 * j + 1] - bf2f(hb));
        }
        #pragma unroll
        for (int Nt = 0; Nt < 8; ++Nt) {
            F8 wh, wl;
            wh.u4 = wfh[ks][Nt][lane];
            wl.u4 = wfl[ks][Nt][lane];
            acc[Nt] = __builtin_amdgcn_mfma_f32_16x16x32_bf16(xh.s, wh.s, acc[Nt], 0, 0, 0);
            acc[Nt] = __builtin_amdgcn_mfma_f32_16x16x32_bf16(xh.s, wl.s, acc[Nt], 0, 0, 0);
            acc[Nt] = __builtin_amdgcn_mfma_f32_16x16x32_bf16(xl.s, wh.s, acc[Nt], 0, 0, 0);
        }
    }
    const int orow = blockIdx.x * 64 + w * 16 + q * 4;
    #pragma unroll
    for (int Nt = 0; Nt < 8; ++Nt)
        #pragma unroll
        for (int r = 0; r < 4; ++r)
            outb[(orow + r) * 128 + Nt * 16 + c] = acc[Nt][r];
}

// ============ Kernel 2: fused neighbor-attention, pipelined MFMA ============
// 512 blocks x 256 thr (4 waves) = 2 blocks/CU co-resident. Wave handles 8
// positions serially. Per position: GEMM1 staging also builds vp=v+pos into a
// per-wave bf16 LDS slab (GEMM2 has zero global loads); next position's pos
// slab + nn_idx prefetched into registers before transform+GEMM2.
__global__ __launch_bounds__(256, 2) void attn_mfma(
    const float* __restrict__ pos, const int* __restrict__ nn_idx,
    const float* __restrict__ qb, const float* __restrict__ kb,
    const float* __restrict__ vb, const float* __restrict__ Wa0,
    const float* __restrict__ Wa1, float* __restrict__ out)
{
    __shared__ uint4 wa0f[16][64];   // Wa0^T A-frags
    __shared__ uint4 wa1f[16][64];   // Wa1 B-frags
    __shared__ __attribute__((aligned(16))) ushort vpL[4][32 * VPS];  // per-wave vp slab

    const int tid  = threadIdx.x;
    const int lane = tid & 63;
    const int w    = tid >> 6;
    const int q    = lane >> 4;
    const int c    = lane & 15;

    for (int e = tid; e < 16 * 64; e += 256) {
        const int f = e >> 6, ln = e & 63;
        const int Mt = f >> 2, ks = f & 3;
        const int lq = ln >> 4, lc = ln & 15;
        const float* wp = Wa0 + (ks * 32 + lq * 8) * 64 + Mt * 16 + lc;
        F8 v;
        #pragma unroll
        for (int j = 0; j < 4; ++j) v.u[j] = pk(wp[(2 * j) * 64], wp[(2 * j + 1) * 64]);
        wa0f[f][ln] = v.u4;
    }
    for (int e = tid; e < 16 * 64; e += 256) {
        const int f = e >> 6, ln = e & 63;
        const int ks = f >> 3, Nt = f & 7;
        const int lq = ln >> 4, lc = ln & 15;
        const float* wp = Wa1 + (ks * 32 + lq * 8) * 128 + Nt * 16 + lc;
        F8 v;
        #pragma unroll
        for (int j = 0; j < 4; ++j) v.u[j] = pk(wp[(2 * j) * 128], wp[(2 * j + 1) * 128]);
        wa1f[f][ln] = v.u4;
    }
    __syncthreads();

    const int pbase = (blockIdx.x * 4 + w) * 8;

    // ---- prefetch pos slab + idx for first position ----
    float4 PF[4][2][2];
    int pidx0, pidx1;
    {
        const int p = pbase;
        pidx0 = nn_idx[p * 32 + c];
        pidx1 = nn_idx[p * 32 + 16 + c];
        #pragma unroll
        for (int ks = 0; ks < 4; ++ks)
            #pragma unroll
            for (int Nt = 0; Nt < 2; ++Nt) {
                const float* pp = pos + ((size_t)(p * 32 + Nt * 16 + c) * 128 + ks * 32 + q * 8);
                PF[ks][Nt][0] = ((const float4*)pp)[0];
                PF[ks][Nt][1] = ((const float4*)pp)[1];
            }
    }

    for (int it = 0; it < 8; ++it) {
        const int p     = pbase + it;
        const int bbase = (p >> 12) << 12;
        const int r0    = (bbase + pidx0) * 128;
        const int r1    = (bbase + pidx1) * 128;

        float4 qv[4][2];
        #pragma unroll
        for (int ks = 0; ks < 4; ++ks) {
            const float* qp = qb + p * 128 + ks * 32 + q * 8;
            qv[ks][0] = ((const float4*)qp)[0];
            qv[ks][1] = ((const float4*)qp)[1];
        }

        // ---- phase A: staging (t + vp) and GEMM1 ----
        floatx4 acc1[4][2];
        #pragma unroll
        for (int i = 0; i < 4; ++i) { acc1[i][0] = {0.f,0.f,0.f,0.f}; acc1[i][1] = {0.f,0.f,0.f,0.f}; }

        #pragma unroll
        for (int ks = 0; ks < 4; ++ks) {
            const int u0 = ks * 32 + q * 8;
            F8 bfrag[2];
            #pragma unroll
            for (int Nt = 0; Nt < 2; ++Nt) {
                const int kr = (Nt ? r1 : r0) + u0;
                const float4 ka = *(const float4*)(kb + kr);
                const float4 kc = *(const float4*)(kb + kr + 4);
                const float4 va = *(const float4*)(vb + kr);
                const float4 vc = *(const float4*)(vb + kr + 4);
                const float4 pa = PF[ks][Nt][0];
                const float4 pc = PF[ks][Nt][1];
                const float4 qa = qv[ks][0], qc = qv[ks][1];
                const float t0 = qa.x - ka.x + pa.x, t1 = qa.y - ka.y + pa.y;
                const float t2 = qa.z - ka.z + pa.z, t3 = qa.w - ka.w + pa.w;
                const float t4 = qc.x - kc.x + pc.x, t5 = qc.y - kc.y + pc.y;
                const float t6 = qc.z - kc.z + pc.z, t7 = qc.w - kc.w + pc.w;
                bfrag[Nt].u[0] = pk(t0, t1); bfrag[Nt].u[1] = pk(t2, t3);
                bfrag[Nt].u[2] = pk(t4, t5); bfrag[Nt].u[3] = pk(t6, t7);
                F8 vpp;
                vpp.u[0] = pk(va.x + pa.x, va.y + pa.y);
                vpp.u[1] = pk(va.z + pa.z, va.w + pa.w);
                vpp.u[2] = pk(vc.x + pc.x, vc.y + pc.y);
                vpp.u[3] = pk(vc.z + pc.z, vc.w + pc.w);
                *(uint4*)&vpL[w][(Nt * 16 + c) * VPS + u0] = vpp.u4;
            }
            #pragma unroll
            for (int Mt = 0; Mt < 4; ++Mt) {
                F8 a1; a1.u4 = wa0f[Mt * 4 + ks][lane];
                acc1[Mt][0] = __builtin_amdgcn_mfma_f32_16x16x32_bf16(a1.s, bfrag[0].s, acc1[Mt][0], 0, 0, 0);
                acc1[Mt][1] = __builtin_amdgcn_mfma_f32_16x16x32_bf16(a1.s, bfrag[1].s, acc1[Mt][1], 0, 0, 0);
            }
        }

        // ---- prefetch next position's pos slab + idx (flies during transform+GEMM2) ----
        {
            const int pn = (p + 1 < BL) ? (p + 1) : p;
            pidx0 = nn_idx[pn * 32 + c];
            pidx1 = nn_idx[pn * 32 + 16 + c];
            #pragma unroll
            for (int ks = 0; ks < 4; ++ks)
                #pragma unroll
                for (int Nt = 0; Nt < 2; ++Nt) {
                    const float* pp = pos + ((size_t)(pn * 32 + Nt * 16 + c) * 128 + ks * 32 + q * 8);
                    PF[ks][Nt][0] = ((const float4*)pp)[0];
                    PF[ks][Nt][1] = ((const float4*)pp)[1];
                }
        }

        // ---- transform: C1-layout H^T -> A2 (H) fragments, with relu (R2-verified) ----
        F8 a2[2][2];
        #pragma unroll
        for (int Mt2 = 0; Mt2 < 2; ++Mt2) {
            #pragma unroll
            for (int ks = 0; ks < 2; ++ks) {
                float vv[8];
                #pragma unroll
                for (int t = 0; t < 8; ++t) {
                    const int sl = c + 16 * ((q & 1) * 2 + (t >> 2));
                    const float vA = __shfl(acc1[2 * ks + 0][Mt2][t & 3], sl, 64);
                    const float vB = __shfl(acc1[2 * ks + 1][Mt2][t & 3], sl, 64);
                    vv[t] = fmaxf((q < 2) ? vA : vB, 0.f);
                }
                #pragma unroll
                for (int j = 0; j < 4; ++j) a2[Mt2][ks].u[j] = pk(vv[2 * j], vv[2 * j + 1]);
            }
        }

        // ---- GEMM2 + fused softmax + weighted sum (vp from LDS) ----
        #pragma unroll
        for (int Nt2 = 0; Nt2 < 8; ++Nt2) {
            F8 b0, b1;
            b0.u4 = wa1f[Nt2][lane];
            b1.u4 = wa1f[8 + Nt2][lane];
            floatx4 a2c[2];
            a2c[0] = {0.f,0.f,0.f,0.f}; a2c[1] = {0.f,0.f,0.f,0.f};
            #pragma unroll
            for (int Mt2 = 0; Mt2 < 2; ++Mt2) {
                a2c[Mt2] = __builtin_amdgcn_mfma_f32_16x16x32_bf16(a2[Mt2][0].s, b0.s, a2c[Mt2], 0, 0, 0);
                a2c[Mt2] = __builtin_amdgcn_mfma_f32_16x16x32_bf16(a2[Mt2][1].s, b1.s, a2c[Mt2], 0, 0, 0);
            }
            const int cg = Nt2 * 16 + c;
            float se = 0.f, ov = 0.f;
            #pragma unroll
            for (int Mt2 = 0; Mt2 < 2; ++Mt2)
                #pragma unroll
                for (int r = 0; r < 4; ++r) {
                    const int   kk = Mt2 * 16 + q * 4 + r;
                    const float e  = __expf(a2c[Mt2][r]);
                    const float vp = bf2f(vpL[w][kk * VPS + cg]);
                    se += e;
                    ov = fmaf(e, vp, ov);
                }
            se += __shfl_xor(se, 16, 64); ov += __shfl_xor(ov, 16, 64);
            se += __shfl_xor(se, 32, 64); ov += __shfl_xor(ov, 32, 64);
            if (q == 0) out[p * 128 + cg] = ov / se;
        }
    }
}

extern "C" void kernel_launch(void* const* d_in, const int* in_sizes, int n_in,
                              void* d_out, int out_size, void* d_ws, size_t ws_size,
                              hipStream_t stream) {
    const float* x    = (const float*)d_in[0];
    const float* pos  = (const float*)d_in[1];
    const int*   nidx = (const int*)  d_in[2];
    const float* Wq   = (const float*)d_in[3];
    const float* Wk   = (const float*)d_in[4];
    const float* Wv   = (const float*)d_in[5];
    const float* Wa0  = (const float*)d_in[6];
    const float* Wa1  = (const float*)d_in[7];
    float* outp = (float*)d_out;

    float* qkvb = (float*)d_ws;
    const float* qbp = qkvb;
    const float* kbp = qkvb + (size_t)BL * 128;
    const float* vbp = qkvb + (size_t)2 * BL * 128;

    qkv_mfma<<<dim3(BL / 64, 3), 256, 0, stream>>>(x, Wq, Wk, Wv, qkvb);
    attn_mfma<<<BL / 8 / 4, 256, 0, stream>>>(pos, nidx, qbp, kbp, vbp, Wa0, Wa1, outp);
}